// Round 9
// baseline (209.275 us; speedup 1.0000x reference)
//
#include <hip/hip_runtime.h>

// SmallRNN: B=4096 chains, T=2048 steps, I=1, H=8, O=1, fp32.
// h_t = tanh(x_t*w_ih + W_hh h_{t-1} + b);  out = fc_w . h_T + fc_b
//
// Round 10: transcendental-free step. R4's counters triangulate
// exp2/rcp at ~21 issue cyc each (58% of issue, ~45% of the recurrence
// cycle). Replace the activation entirely:
//   tanh(z) ~= z*N(y)/D(y), y = z^2   (Pade(7,6), exact CF integers)
//     N = 135135 + 17325 y + 378 y^2 + y^3
//     D = 135135 + 62370 y + 3150 y^2 + 28 y^3
//   err: 5e-6 @z=3, 4e-4 @z=6; input clamped to [-6,6] (|pre|<~5.5).
//   1/D via magic-constant seed (0x7EF127EA - as_int(D), rel err <~10%)
//   + 2 Newton steps -> rel err < 1e-4. Total act err ~5e-4/step,
//   final-output error ~1e-3 << 2.64e-2 threshold.
// Step: 29 full-rate ops, ZERO trans: issue 72 -> 58 cyc, cycle ~100 ->
// ~80. Pure C + builtins only (R5/R7/R8: all asm variants lost to
// scheduler opacity/hazards). h-state restored (no C/r-state folds).
// R4's exact loop & dot shape kept (R9: reshuffles of same ops regress).
//
// Closed paths (measured): R6 2x-wave replication (single issue port,
// 92->154); R5 asm DPP-fusion (hazard corruption); R7/R8 pk-asm
// (94.7/115.9); R9 shallow dot (99.0).
//
// Layout (R4-verified): 16 lanes/chain, 8 rows x 2 column-split
// replicas; lane p holds h[rho], rho=j^(4*(p>=8)); computes 4-col
// partials for rows rho (P1, xwb seed) and rho^4 (P2), P2 exchanged
// via row_ror:8 (+-8 mod 16 == XOR8 either way). 256 thr/block =
// 16 chains, grid 256 -> 1024 waves = 1 wave/SIMD.

#define B_TOTAL 4096
#define T_STEPS 2048
#define H 8

template <int CTRL>
__device__ __forceinline__ float dppf(float v) {
    int i = __float_as_int(v);
    i = __builtin_amdgcn_mov_dpp(i, CTRL, 0xF, 0xF, true);
    return __int_as_float(i);
}

__global__ __launch_bounds__(256, 1) void rnn_fused(
    const float* __restrict__ x,      // [4096, 2048]
    const float* __restrict__ w_ih,   // [8,1]
    const float* __restrict__ w_hh,   // [8,8]
    const float* __restrict__ b_ih,   // [8]
    const float* __restrict__ b_hh,   // [8]
    const float* __restrict__ fc_w,   // [1,8]
    const float* __restrict__ fc_b,   // [1]
    float* __restrict__ out)          // [4096,1]
{
    const int tid      = threadIdx.x;
    const int p        = tid & 15;          // position within 16-lane row
    const int j        = p & 7;             // hidden index within replica
    const int rho      = j ^ ((p >> 3) << 2); // rotated row: j ^ 4 for high replica
    const int chain    = (blockIdx.x << 4) + (tid >> 4);
    const int baseLane = tid & 48;          // wave-relative base of this row

    // Plain h-state weights (no folds needed with direct tanh):
    //   wA[k] = W[rho  ][rho^k]  (own row,     xwb seed)
    //   wB[k] = W[rho^4][rho^k]  (partner row, ror:8 exchange)
    float wA[4], wB[4];
#pragma unroll
    for (int k = 0; k < 4; ++k) {
        wA[k] = w_hh[rho * H + (rho ^ k)];
        wB[k] = w_hh[(rho ^ 4) * H + (rho ^ k)];
    }
    const float wih  = w_ih[rho];
    const float bsum = b_ih[rho] + b_hh[rho];

    const float* xp = x + (size_t)chain * T_STEPS;

    float h = 0.0f;   // h0 = 0

    // One RNN step, all full-rate VALU (no trans):
    //   xwb | 3 quad_perm gathers | R4 dual 4-deep fma dot | ror:8
    //   exchange | z=p1+p2x | clamp | Pade(7,6): N,D cubics in y=z^2 |
    //   1/D: magic seed + 2 Newton | h = z*N * (1/D).
#define STEP(xval)                                            \
    {                                                         \
        float xwb = fmaf((xval), wih, bsum); /* off-path */   \
        float g1 = dppf<0xB1>(h);    /* h[rho^1] */           \
        float g2 = dppf<0x4E>(h);    /* h[rho^2] */           \
        float g3 = dppf<0x1B>(h);    /* h[rho^3] */           \
        float p2 = wB[0] * h;                                 \
        float p1 = fmaf(wA[0], h, xwb);                       \
        p2 = fmaf(wB[1], g1, p2);                             \
        p1 = fmaf(wA[1], g1, p1);                             \
        p2 = fmaf(wB[2], g2, p2);                             \
        p1 = fmaf(wA[2], g2, p1);                             \
        p2 = fmaf(wB[3], g3, p2);                             \
        p1 = fmaf(wA[3], g3, p1);                             \
        float p2x = dppf<0x128>(p2); /* partner P2 (XOR8) */  \
        float z = p1 + p2x;                                   \
        z = fminf(fmaxf(z, -6.0f), 6.0f);                     \
        float y = z * z;                                      \
        float nt = y + 378.0f;                                \
        nt = fmaf(nt, y, 17325.0f);                           \
        nt = fmaf(nt, y, 135135.0f);                          \
        float dt = fmaf(28.0f, y, 3150.0f);                   \
        dt = fmaf(dt, y, 62370.0f);                           \
        dt = fmaf(dt, y, 135135.0f);                          \
        float nn = z * nt;                                    \
        float y0 = __int_as_float(0x7EF127EA -                \
                                  __float_as_int(dt));        \
        y0 = y0 * fmaf(-dt, y0, 2.0f);                        \
        y0 = y0 * fmaf(-dt, y0, 2.0f);                        \
        h = nn * y0;                                          \
    }

    // 16-step unroll; prefetch the next 16 x-values a full group ahead
    // (R4's verified loop shape).
    float4 c0 = *(const float4*)(xp + 0);
    float4 c1v = *(const float4*)(xp + 4);
    float4 c2v = *(const float4*)(xp + 8);
    float4 c3v = *(const float4*)(xp + 12);

    for (int t = 0; t < T_STEPS; t += 16) {
        float4 n0 = c0, n1 = c1v, n2 = c2v, n3 = c3v;
        if (t + 16 < T_STEPS) {
            n0 = *(const float4*)(xp + t + 16);
            n1 = *(const float4*)(xp + t + 20);
            n2 = *(const float4*)(xp + t + 24);
            n3 = *(const float4*)(xp + t + 28);
        }
        STEP(c0.x) STEP(c0.y) STEP(c0.z) STEP(c0.w)
        STEP(c1v.x) STEP(c1v.y) STEP(c1v.z) STEP(c1v.w)
        STEP(c2v.x) STEP(c2v.y) STEP(c2v.z) STEP(c2v.w)
        STEP(c3v.x) STEP(c3v.y) STEP(c3v.z) STEP(c3v.w)
        c0 = n0; c1v = n1; c2v = n2; c3v = n3;
    }
#undef STEP

    // Epilogue: lanes p=0..7 hold h[rho]=h[0..7] (low replica).
    float g[H];
#pragma unroll
    for (int k = 0; k < H; ++k) g[k] = __shfl(h, baseLane + k);
    if (p == 0) {
        float o = fc_b[0];
#pragma unroll
        for (int k = 0; k < H; ++k) o = fmaf(fc_w[k], g[k], o);
        out[chain] = o;
    }
}

extern "C" void kernel_launch(void* const* d_in, const int* in_sizes, int n_in,
                              void* d_out, int out_size, void* d_ws, size_t ws_size,
                              hipStream_t stream) {
    const float* x    = (const float*)d_in[0];
    const float* w_ih = (const float*)d_in[1];
    const float* w_hh = (const float*)d_in[2];
    const float* b_ih = (const float*)d_in[3];
    const float* b_hh = (const float*)d_in[4];
    const float* fc_w = (const float*)d_in[5];
    const float* fc_b = (const float*)d_in[6];
    float* out = (float*)d_out;

    dim3 grid(B_TOTAL / 16);   // 256 blocks -> 1 per CU
    dim3 block(256);           // 4 waves -> 1 per SIMD
    hipLaunchKernelGGL(rnn_fused, grid, block, 0, stream,
                       x, w_ih, w_hh, b_ih, b_hh, fc_w, fc_b, out);
}

// Round 10
// 157.677 us; speedup vs baseline: 1.3272x; 1.3272x over previous
//
#include <hip/hip_runtime.h>

// SmallRNN: B=4096 chains, T=2048 steps, I=1, H=8, O=1, fp32.
// h_t = tanh(x_t*w_ih + W_hh h_{t-1} + b);  out = fc_w . h_T + fc_b
//
// Round 11: REVERT to the R4-verified anchor (92.0 us/dispatch, 157.5 us
// bench) after R10's Pade-act regression (154 us: 13-deep dependent
// fp32 chain at ~4cyc/op latency loses to HW transcendentals on both
// issue and chain).
//
// Measured-closed levers (this session):
//   R5  asm DPP-fusion        -> hazard corruption (DPP reads need 2
//                                wait states; asm defeats compiler's)
//   R6  2 waves/SIMD replica  -> 154 us (single issue port per SIMD)
//   R7  serial pk_fma asm     -> 94.7 us (volatile chain, no ILP)
//   R8  pk ILP asm block      -> 115.9 us (block atomic to scheduler)
//   R9  shallow dot + add3    -> 99.0 us (R4 shape = sched optimum)
//   R10 Pade+Newton act       -> 154.4 us (dependent-chain latency)
// Model: 108 cyc/step = 73 issue (15 full-rate ops + 2 trans x ~21.5)
// + 35 serial trans-latency residue, unfillable at 1 wave/SIMD with
// zero spare same-wave ILP. Issue floor 62 us unreachable.
//
// Layout: 16 lanes/chain (8 rows x 2 column-split replicas). Lane p
// holds r[rho], rho = j ^ 4*(p>=8); computes 4-column partials for
// rows rho (P1, xwb seed) and rho^4 (P2, exchanged via row_ror:8 --
// +-8 mod 16 == XOR8 either direction). r-state: r = 1/(1+exp2(C*pre)),
// h = 1-2r folded into W', b' (C = 2*log2 e). 256 thr/block = 16
// chains, grid 256 -> 1024 waves = 1 wave/SIMD on all 256 CUs.

#define B_TOTAL 4096
#define T_STEPS 2048
#define H 8

template <int CTRL>
__device__ __forceinline__ float dppf(float v) {
    int i = __float_as_int(v);
    i = __builtin_amdgcn_mov_dpp(i, CTRL, 0xF, 0xF, true);
    return __int_as_float(i);
}

__global__ __launch_bounds__(256, 1) void rnn_fused(
    const float* __restrict__ x,      // [4096, 2048]
    const float* __restrict__ w_ih,   // [8,1]
    const float* __restrict__ w_hh,   // [8,8]
    const float* __restrict__ b_ih,   // [8]
    const float* __restrict__ b_hh,   // [8]
    const float* __restrict__ fc_w,   // [1,8]
    const float* __restrict__ fc_b,   // [1]
    float* __restrict__ out)          // [4096,1]
{
    const int tid      = threadIdx.x;
    const int p        = tid & 15;          // position within 16-lane row
    const int j        = p & 7;             // hidden index within replica
    const int rho      = j ^ ((p >> 3) << 2); // rotated row: j ^ 4 for high replica
    const int chain    = (blockIdx.x << 4) + (tid >> 4);
    const int baseLane = tid & 48;          // wave-relative base of this row

    // C = 2*log2(e): exp(2*pre) = exp2(C*pre).
    const float C = 2.885390081777927f;

    // r-state weights (r = 1/(1+exp2(C*pre)), h = 1-2r folded into W,b):
    //   W'[row][col] = -2*C*W[row][col]
    //   bP_row = C*(b_row + rowsum(W[row])),  wihC_row = C*wih_row
    // Lane p covers columns rho^{0..3}:
    //   wA[k] = W'[rho  ][rho^k]   (own row,    seeded with xwb)
    //   wB[k] = W'[rho^4][rho^k]   (partner row, exchanged via ror:8)
    float wA[4], wB[4];
    float rowsum = 0.0f;
#pragma unroll
    for (int i = 0; i < H; ++i) rowsum += w_hh[rho * H + i];
#pragma unroll
    for (int k = 0; k < 4; ++k) {
        wA[k] = -2.0f * C * w_hh[rho * H + (rho ^ k)];
        wB[k] = -2.0f * C * w_hh[(rho ^ 4) * H + (rho ^ k)];
    }
    const float wihC = C * w_ih[rho];
    const float bP   = C * (b_ih[rho] + b_hh[rho] + rowsum);

    const float* xp = x + (size_t)chain * T_STEPS;

    float r = 0.5f;   // h = 1 - 2r = 0 for every row

    // One RNN step: 3 quad_perm gathers (depth 1), two 4-term partial
    // chains, one ror:8 exchange, one add, then exp2 + add + rcp.
    // Builtins only -- compiler inserts DPP wait states and software-
    // pipelines across the 16-step unroll (every deviation regressed).
#define STEP(xval)                                          \
    {                                                       \
        float xwb = fmaf((xval), wihC, bP);  /* off-path */ \
        float g1 = dppf<0xB1>(r);    /* r[rho^1] */         \
        float g2 = dppf<0x4E>(r);    /* r[rho^2] */         \
        float g3 = dppf<0x1B>(r);    /* r[rho^3] */         \
        float p2 = wB[0] * r;                               \
        float p1 = fmaf(wA[0], r, xwb);                     \
        p2 = fmaf(wB[1], g1, p2);                           \
        p1 = fmaf(wA[1], g1, p1);                           \
        p2 = fmaf(wB[2], g2, p2);                           \
        p1 = fmaf(wA[2], g2, p1);                           \
        p2 = fmaf(wB[3], g3, p2);                           \
        p1 = fmaf(wA[3], g3, p1);                           \
        float p2x = dppf<0x128>(p2); /* partner's P2 (XOR8) */ \
        float s = p1 + p2x;                                 \
        float e = __builtin_amdgcn_exp2f(s);                \
        r = __builtin_amdgcn_rcpf(1.0f + e);                \
    }

    // 16-step unroll; prefetch the next 16 x-values a full group ahead.
    float4 c0 = *(const float4*)(xp + 0);
    float4 c1v = *(const float4*)(xp + 4);
    float4 c2v = *(const float4*)(xp + 8);
    float4 c3v = *(const float4*)(xp + 12);

    for (int t = 0; t < T_STEPS; t += 16) {
        float4 n0 = c0, n1 = c1v, n2 = c2v, n3 = c3v;
        if (t + 16 < T_STEPS) {
            n0 = *(const float4*)(xp + t + 16);
            n1 = *(const float4*)(xp + t + 20);
            n2 = *(const float4*)(xp + t + 24);
            n3 = *(const float4*)(xp + t + 28);
        }
        STEP(c0.x) STEP(c0.y) STEP(c0.z) STEP(c0.w)
        STEP(c1v.x) STEP(c1v.y) STEP(c1v.z) STEP(c1v.w)
        STEP(c2v.x) STEP(c2v.y) STEP(c2v.z) STEP(c2v.w)
        STEP(c3v.x) STEP(c3v.y) STEP(c3v.z) STEP(c3v.w)
        c0 = n0; c1v = n1; c2v = n2; c3v = n3;
    }
#undef STEP

    // Final h from r-state; lanes p=0..7 hold rows rho=0..7 (low replica).
    float h = fmaf(-2.0f, r, 1.0f);
    float g[H];
#pragma unroll
    for (int k = 0; k < H; ++k) g[k] = __shfl(h, baseLane + k);
    if (p == 0) {
        float o = fc_b[0];
#pragma unroll
        for (int k = 0; k < H; ++k) o = fmaf(fc_w[k], g[k], o);
        out[chain] = o;
    }
}

extern "C" void kernel_launch(void* const* d_in, const int* in_sizes, int n_in,
                              void* d_out, int out_size, void* d_ws, size_t ws_size,
                              hipStream_t stream) {
    const float* x    = (const float*)d_in[0];
    const float* w_ih = (const float*)d_in[1];
    const float* w_hh = (const float*)d_in[2];
    const float* b_ih = (const float*)d_in[3];
    const float* b_hh = (const float*)d_in[4];
    const float* fc_w = (const float*)d_in[5];
    const float* fc_b = (const float*)d_in[6];
    float* out = (float*)d_out;

    dim3 grid(B_TOTAL / 16);   // 256 blocks -> 1 per CU
    dim3 block(256);           // 4 waves -> 1 per SIMD
    hipLaunchKernelGGL(rnn_fused, grid, block, 0, stream,
                       x, w_ih, w_hh, b_ih, b_hh, fc_w, fc_b, out);
}